// Round 5
// baseline (64.027 us; speedup 1.0000x reference)
//
#include <hip/hip_runtime.h>
#include <cstddef>

#define B_ 32
#define N_ 128
#define D_ 128
#define NEG_SLOPE 0.01f

typedef float v4f __attribute__((ext_vector_type(4)));

// One block per (b,i), 256 threads.
// Phase 1 (hot): pure value stream — value[b,i,j,d] = e[b,i,d]*e[b,j,d],
//   plain v4f stores (L2 write-combining path), fully unrolled, no cross-lane ops.
// Phase 2 (cheap): scores via h = ei*w staged in LDS, dot with ej rows
//   (L1/L2-resident), leakyrelu, softmax over j, write alphas.
__global__ void __launch_bounds__(256)
fused_value_attn_kernel(const float* __restrict__ e,
                        const float* __restrict__ w,
                        const float* __restrict__ bias,
                        float* __restrict__ alphas,
                        float* __restrict__ value) {
    const int bi = blockIdx.x;          // b*N + i
    const int b  = bi >> 7;
    const int t  = threadIdx.x;
    const int d4 = t & 31;              // v4f index within D=128 row
    const int jg = t >> 5;              // 0..7

    __shared__ float h[D_];             // ei * w
    __shared__ float ph[256];           // per-thread partial dots
    __shared__ float red[N_];

    const v4f* __restrict__ e4 = reinterpret_cast<const v4f*>(e);
    const v4f ei4 = e4[(size_t)bi * 32 + d4];

    v4f* __restrict__ vout = reinterpret_cast<v4f*>(
        value + (size_t)bi * N_ * D_);

    // ---- Phase 1: streaming value writes (the 256 MB) ----
#pragma unroll
    for (int jj = 0; jj < 16; ++jj) {
        const int j = (jj << 3) + jg;   // 0..127
        const v4f ej4 = e4[((size_t)((b << 7) | j)) * 32 + d4];
        vout[(j << 5) + d4] = ei4 * ej4;
    }

    // ---- Phase 2: scores + softmax (tiny, cache-resident) ----
    if (t < N_) h[t] = e[(size_t)bi * D_ + t] * w[t];
    __syncthreads();

    // 256 threads: j = t&127, half = t>>7 covers d in [half*64, half*64+64)
    const int j2   = t & 127;
    const int half = t >> 7;
    const float* __restrict__ ejrow = e + ((size_t)((b << 7) | j2)) * D_ + (half << 6);
    const float* __restrict__ hrow  = h + (half << 6);
    float p = 0.f;
#pragma unroll
    for (int q = 0; q < 16; ++q) {
        const v4f ejv = *reinterpret_cast<const v4f*>(ejrow + (q << 2));
        const v4f hv  = *reinterpret_cast<const v4f*>(hrow + (q << 2));
        const v4f pr  = hv * ejv;
        p += pr.x + pr.y + pr.z + pr.w;
    }
    ph[t] = p;
    __syncthreads();

    float s = 0.f, ex = 0.f;
    if (t < N_) {
        s = ph[t] + ph[t + 128] + bias[0];
        s = (s >= 0.f) ? s : NEG_SLOPE * s;
        red[t] = s;
    }
    __syncthreads();
#pragma unroll
    for (int off = 64; off > 0; off >>= 1) {
        if (t < off) red[t] = fmaxf(red[t], red[t + off]);
        __syncthreads();
    }
    const float m = red[0];
    __syncthreads();
    if (t < N_) { ex = expf(s - m); red[t] = ex; }
    __syncthreads();
#pragma unroll
    for (int off = 64; off > 0; off >>= 1) {
        if (t < off) red[t] += red[t + off];
        __syncthreads();
    }
    if (t < N_) alphas[(size_t)bi * N_ + t] = ex / red[0];
}

extern "C" void kernel_launch(void* const* d_in, const int* in_sizes, int n_in,
                              void* d_out, int out_size, void* d_ws, size_t ws_size,
                              hipStream_t stream) {
    const float* e    = (const float*)d_in[0];   // [B, N, D]
    const float* w    = (const float*)d_in[1];   // [D]
    const float* bias = (const float*)d_in[2];   // [1]

    float* out    = (float*)d_out;
    float* alphas = out;                              // B*N*N
    float* value  = out + (size_t)B_ * N_ * N_;       // B*N*N*D

    fused_value_attn_kernel<<<B_ * N_, 256, 0, stream>>>(e, w, bias, alphas, value);
}

// Round 6
// 58.218 us; speedup vs baseline: 1.0998x; 1.0998x over previous
//
#include <hip/hip_runtime.h>
#include <cstddef>

#define B_ 32
#define N_ 128
#define D_ 128
#define NEG_SLOPE 0.01f

typedef float v4f __attribute__((ext_vector_type(4)));

// R2 structure (best: 49.7us) with ONE change: nontemporal value stores.
// One block per (b,i): 256 threads, t -> (d4 = t&31, jg = t>>5).
// 16 iterations (unroll 4) over j. Score dot reuses the v4 already computed.
__global__ void __launch_bounds__(256)
fused_value_attn_kernel(const float* __restrict__ e,
                        const float* __restrict__ w,
                        const float* __restrict__ bias,
                        float* __restrict__ alphas,
                        float* __restrict__ value) {
    const int bi = blockIdx.x;          // b*N + i
    const int b  = bi >> 7;
    const int t  = threadIdx.x;
    const int d4 = t & 31;              // which v4f of the D=128 row
    const int jg = t >> 5;              // 0..7

    __shared__ float sc[N_];
    __shared__ float red[N_];

    const v4f* __restrict__ e4 = reinterpret_cast<const v4f*>(e);
    const v4f w4  = reinterpret_cast<const v4f*>(w)[d4];
    const v4f ei4 = e4[(size_t)bi * 32 + d4];
    const float bias0 = bias[0];

    v4f* __restrict__ vout = reinterpret_cast<v4f*>(
        value + (size_t)bi * N_ * D_);

#pragma unroll 4
    for (int jj = 0; jj < 16; ++jj) {
        const int j = (jj << 3) + jg;   // 0..127
        const v4f ej4 = e4[((size_t)((b << 7) | j)) * 32 + d4];
        const v4f v4 = ei4 * ej4;

        __builtin_nontemporal_store(v4, &vout[(j << 5) + d4]);

        // partial score: sum_d v[d]*w[d] over this thread's 4 d's
        const v4f pw = v4 * w4;
        float p = pw.x + pw.y + pw.z + pw.w;
        // butterfly over the 32 lanes sharing this j
        p += __shfl_xor(p, 1);
        p += __shfl_xor(p, 2);
        p += __shfl_xor(p, 4);
        p += __shfl_xor(p, 8);
        p += __shfl_xor(p, 16);
        if (d4 == 0) sc[j] = p;
    }
    __syncthreads();

    // Softmax over j (threads 0..127 own one j each; all threads hit barriers)
    float s = 0.f, ex = 0.f;
    if (t < N_) {
        s = sc[t] + bias0;
        s = (s >= 0.f) ? s : NEG_SLOPE * s;
        red[t] = s;
    }
    __syncthreads();
#pragma unroll
    for (int off = 64; off > 0; off >>= 1) {
        if (t < off) red[t] = fmaxf(red[t], red[t + off]);
        __syncthreads();
    }
    const float m = red[0];
    __syncthreads();
    if (t < N_) { ex = expf(s - m); red[t] = ex; }
    __syncthreads();
#pragma unroll
    for (int off = 64; off > 0; off >>= 1) {
        if (t < off) red[t] += red[t + off];
        __syncthreads();
    }
    if (t < N_) alphas[(size_t)bi * N_ + t] = ex / red[0];
}

extern "C" void kernel_launch(void* const* d_in, const int* in_sizes, int n_in,
                              void* d_out, int out_size, void* d_ws, size_t ws_size,
                              hipStream_t stream) {
    const float* e    = (const float*)d_in[0];   // [B, N, D]
    const float* w    = (const float*)d_in[1];   // [D]
    const float* bias = (const float*)d_in[2];   // [1]

    float* out    = (float*)d_out;
    float* alphas = out;                              // B*N*N
    float* value  = out + (size_t)B_ * N_ * N_;       // B*N*N*D

    fused_value_attn_kernel<<<B_ * N_, 256, 0, stream>>>(e, w, bias, alphas, value);
}

// Round 7
// 49.861 us; speedup vs baseline: 1.2841x; 1.1676x over previous
//
#include <hip/hip_runtime.h>
#include <cstddef>

#define B_ 32
#define N_ 128
#define D_ 128
#define IT 4
#define NEG_SLOPE 0.01f

typedef float v4f __attribute__((ext_vector_type(4)));

// One block per (b, 4 consecutive i). 256 threads: d4 = t&31 (v4f in D row),
// jg = t>>5 (0..7). Hot loop (16 iters): load ej once -> 4 stores (one per i'),
// score partials via h=ei*w registers + 5-shfl butterfly (proven R2 interleave).
// Tail: per-wave shfl softmax, one row per wave.
__global__ void __launch_bounds__(256)
fused_value_attn_kernel(const float* __restrict__ e,
                        const float* __restrict__ w,
                        const float* __restrict__ bias,
                        float* __restrict__ alphas,
                        float* __restrict__ value) {
    const int blk = blockIdx.x;            // b * (N/IT) + itile
    const int b   = blk >> 5;              // N/IT = 32
    const int i0  = (blk & 31) << 2;       // IT = 4
    const int t   = threadIdx.x;
    const int d4  = t & 31;
    const int jg  = t >> 5;

    __shared__ float sc[IT][N_];

    const v4f* __restrict__ e4 = reinterpret_cast<const v4f*>(e);
    const v4f w4 = reinterpret_cast<const v4f*>(w)[d4];

    v4f ei4[IT], h4[IT];
    v4f* vptr[IT];
#pragma unroll
    for (int q = 0; q < IT; ++q) {
        const int bi = (b << 7) | (i0 + q);
        ei4[q] = e4[(size_t)bi * 32 + d4];
        h4[q]  = ei4[q] * w4;              // for score dot: sum(v*w) = sum(h*ej)
        vptr[q] = reinterpret_cast<v4f*>(value + (size_t)bi * N_ * D_);
    }

#pragma unroll 4
    for (int jj = 0; jj < 16; ++jj) {
        const int j = (jj << 3) + jg;      // 0..127
        const v4f ej4 = e4[((size_t)((b << 7) | j)) * 32 + d4];
#pragma unroll
        for (int q = 0; q < IT; ++q) {
            vptr[q][(j << 5) + d4] = ei4[q] * ej4;
            const v4f pw = h4[q] * ej4;
            float p = pw.x + pw.y + pw.z + pw.w;
            p += __shfl_xor(p, 1);
            p += __shfl_xor(p, 2);
            p += __shfl_xor(p, 4);
            p += __shfl_xor(p, 8);
            p += __shfl_xor(p, 16);
            if (d4 == 0) sc[q][j] = p;
        }
    }
    __syncthreads();

    // Softmax: wave wv owns row i0+wv (IT == #waves == 4). Lane l handles
    // j = l and j = l+64. Full-wave shfl reductions, no more barriers.
    const int wv = t >> 6;
    const int l  = t & 63;
    const float bias0 = bias[0];
    float s0 = sc[wv][l]      + bias0;
    float s1 = sc[wv][l + 64] + bias0;
    s0 = (s0 >= 0.f) ? s0 : NEG_SLOPE * s0;
    s1 = (s1 >= 0.f) ? s1 : NEG_SLOPE * s1;
    float m = fmaxf(s0, s1);
#pragma unroll
    for (int off = 32; off > 0; off >>= 1) m = fmaxf(m, __shfl_xor(m, off));
    const float e0 = expf(s0 - m), e1 = expf(s1 - m);
    float sum = e0 + e1;
#pragma unroll
    for (int off = 32; off > 0; off >>= 1) sum += __shfl_xor(sum, off);
    const float inv = 1.f / sum;
    float* arow = alphas + ((size_t)((b << 7) | (i0 + wv))) * N_;
    arow[l]      = e0 * inv;
    arow[l + 64] = e1 * inv;
}

extern "C" void kernel_launch(void* const* d_in, const int* in_sizes, int n_in,
                              void* d_out, int out_size, void* d_ws, size_t ws_size,
                              hipStream_t stream) {
    const float* e    = (const float*)d_in[0];   // [B, N, D]
    const float* w    = (const float*)d_in[1];   // [D]
    const float* bias = (const float*)d_in[2];   // [1]

    float* out    = (float*)d_out;
    float* alphas = out;                              // B*N*N
    float* value  = out + (size_t)B_ * N_ * N_;       // B*N*N*D

    fused_value_attn_kernel<<<(B_ * N_) / IT, 256, 0, stream>>>(e, w, bias, alphas, value);
}